// Round 1
// baseline (518.679 us; speedup 1.0000x reference)
//
#include <hip/hip_runtime.h>
#include <hip/hip_bf16.h>
#include <hip/hip_fp16.h>

#define SEQ    2048
#define DMODEL 2048
#define NH     16
#define NKV    4
#define HD     128
#define NTOT   3072   // DMODEL + 2*NKV*HD
#define MROWS  4096   // B*SEQ

typedef __attribute__((ext_vector_type(4))) float f32x4;
typedef __attribute__((ext_vector_type(8))) __bf16 bf16x8;

__device__ __forceinline__ void async_copy16(const void* g, void* l) {
  __builtin_amdgcn_global_load_lds(
      (const __attribute__((address_space(1))) void*)g,
      (__attribute__((address_space(3))) void*)l, 16, 0, 0);
}

__device__ __forceinline__ unsigned short fto16(float f) {
  __hip_bfloat16 h = __float2bfloat16(f);
  return *(unsigned short*)&h;
}

// ---------------- fake-quant: one wave per 128-elem block ----------------
__global__ __launch_bounds__(256) void fq_kernel(const float* __restrict__ W,
                                                 unsigned short* __restrict__ out,
                                                 int n128) {
  int blk = blockIdx.x * 4 + (threadIdx.x >> 6);
  if (blk >= n128) return;
  int lane = threadIdx.x & 63;
  const float* p = W + (size_t)blk * 128 + lane * 2;
  float w0 = p[0], w1 = p[1];
  float m = fmaxf(fabsf(w0), fabsf(w1));
#pragma unroll
  for (int o = 32; o; o >>= 1) m = fmaxf(m, __shfl_xor(m, o));
  float s = fmaxf(m / 31.0f, 1e-12f);
  s = __half2float(__float2half(s));        // fp16 RNE round of scale
  s = fmaxf(s, 6.103515625e-05f);           // fp16 tiny
  float q0 = rintf(fminf(fmaxf(w0 / s, -32.0f), 31.0f)) * s;
  float q1 = rintf(fminf(fmaxf(w1 / s, -32.0f), 31.0f)) * s;
  unsigned short* o16 = out + (size_t)blk * 128 + lane * 2;
  o16[0] = fto16(q0);
  o16[1] = fto16(q1);
}

// ---------------- fp32 -> bf16 convert ----------------
__global__ __launch_bounds__(256) void conv_kernel(const float* __restrict__ in,
                                                   unsigned short* __restrict__ out,
                                                   int n) {
  int i = (blockIdx.x * blockDim.x + threadIdx.x) * 4;
  if (i >= n) return;
  float4 v = *(const float4*)(in + i);
  ushort4 o;
  o.x = fto16(v.x); o.y = fto16(v.y); o.z = fto16(v.z); o.w = fto16(v.w);
  *(ushort4*)(out + i) = o;
}

// ---------------- bf16 MFMA GEMM, C[m,n] = sum_k A[m,k]*B[n,k] ----------------
#define BM 128
#define BN 128
#define BK 32
__global__ __launch_bounds__(256) void gemm_bt(const unsigned short* __restrict__ A,
                                               const unsigned short* __restrict__ Bm,
                                               float* __restrict__ C,
                                               int M, int N, int K) {
  __shared__ unsigned short As[BM * BK];
  __shared__ unsigned short Bs[BN * BK];
  const int tid = threadIdx.x;
  const int wave = tid >> 6, lane = tid & 63;
  const int quad = lane >> 4, l16 = lane & 15;
  const int m0 = blockIdx.x * BM, n0 = blockIdx.y * BN;
  const int wm = (wave >> 1) * 64, wn = (wave & 1) * 64;
  const int sr = lane >> 2, sc = (lane & 3) * 8;

  const unsigned short* Ag = A + (size_t)m0 * K;
  const unsigned short* Bg = Bm + (size_t)n0 * K;

  f32x4 acc[4][4];
#pragma unroll
  for (int i = 0; i < 4; i++)
#pragma unroll
    for (int j = 0; j < 4; j++) acc[i][j] = f32x4{0.f, 0.f, 0.f, 0.f};

  const int seg0 = wave * 2, seg1 = wave * 2 + 1;
  unsigned short* lA0 = &As[seg0 * 16 * BK];
  unsigned short* lA1 = &As[seg1 * 16 * BK];
  unsigned short* lB0 = &Bs[seg0 * 16 * BK];
  unsigned short* lB1 = &Bs[seg1 * 16 * BK];
  const unsigned short* gA0 = Ag + (size_t)(seg0 * 16 + sr) * K + sc;
  const unsigned short* gA1 = Ag + (size_t)(seg1 * 16 + sr) * K + sc;
  const unsigned short* gB0 = Bg + (size_t)(seg0 * 16 + sr) * K + sc;
  const unsigned short* gB1 = Bg + (size_t)(seg1 * 16 + sr) * K + sc;

  for (int k0 = 0; k0 < K; k0 += BK) {
    __syncthreads();
    async_copy16(gA0 + k0, lA0);
    async_copy16(gA1 + k0, lA1);
    async_copy16(gB0 + k0, lB0);
    async_copy16(gB1 + k0, lB1);
    __syncthreads();
    bf16x8 af[4], bf[4];
#pragma unroll
    for (int t = 0; t < 4; t++)
      af[t] = *(const bf16x8*)&As[(wm + t * 16 + l16) * BK + quad * 8];
#pragma unroll
    for (int t = 0; t < 4; t++)
      bf[t] = *(const bf16x8*)&Bs[(wn + t * 16 + l16) * BK + quad * 8];
#pragma unroll
    for (int i = 0; i < 4; i++)
#pragma unroll
      for (int j = 0; j < 4; j++)
        acc[i][j] = __builtin_amdgcn_mfma_f32_16x16x32_bf16(af[i], bf[j], acc[i][j], 0, 0, 0);
  }
#pragma unroll
  for (int i = 0; i < 4; i++) {
    int row_base = m0 + wm + i * 16 + quad * 4;
#pragma unroll
    for (int j = 0; j < 4; j++) {
      int col = n0 + wn + j * 16 + l16;
#pragma unroll
      for (int r = 0; r < 4; r++)
        C[(size_t)(row_base + r) * N + col] = acc[i][j][r];
    }
  }
}

// ---------------- RMSNorm + RoPE + gain, bf16 emit in (b,h,s,d) ----------------
__global__ __launch_bounds__(256) void normrope_kernel(const float* __restrict__ qkv,
                                                       const float* __restrict__ qgain,
                                                       unsigned short* __restrict__ qbuf,
                                                       unsigned short* __restrict__ kbuf,
                                                       unsigned short* __restrict__ vbuf) {
  const int i = blockIdx.x;            // token 0..4095
  const int bz = i >> 11, tok = i & 2047;
  const int wave = threadIdx.x >> 6, lane = threadIdx.x & 63;
  const float* row = qkv + (size_t)i * NTOT;

  double invf = pow(10000.0, -(double)(2 * lane) / 128.0);
  float freq = (float)((double)tok * invf);
  float cs = cosf(freq), sn = sinf(freq);

  for (int slot = wave; slot < 24; slot += 4) {
    if (slot < 16) {                   // q heads: norm + rope + gain
      int hh = slot;
      const float* src = row + hh * HD;
      float x1 = src[lane], x2 = src[lane + 64];
      float ss = x1 * x1 + x2 * x2;
#pragma unroll
      for (int o = 32; o; o >>= 1) ss += __shfl_xor(ss, o);
      float rn = rsqrtf(ss * (1.0f / 128.0f) + 1.1920929e-07f);
      float n1 = x1 * rn, n2 = x2 * rn;
      float g = qgain[hh];
      unsigned short* dst = qbuf + ((size_t)(bz * NH + hh) * SEQ + tok) * HD;
      dst[lane]      = fto16((n1 * cs + n2 * sn) * g);
      dst[lane + 64] = fto16((-n1 * sn + n2 * cs) * g);
    } else if (slot < 20) {            // k heads: norm + rope
      int hh = slot - 16;
      const float* src = row + DMODEL + hh * HD;
      float x1 = src[lane], x2 = src[lane + 64];
      float ss = x1 * x1 + x2 * x2;
#pragma unroll
      for (int o = 32; o; o >>= 1) ss += __shfl_xor(ss, o);
      float rn = rsqrtf(ss * (1.0f / 128.0f) + 1.1920929e-07f);
      float n1 = x1 * rn, n2 = x2 * rn;
      unsigned short* dst = kbuf + ((size_t)(bz * NKV + hh) * SEQ + tok) * HD;
      dst[lane]      = fto16(n1 * cs + n2 * sn);
      dst[lane + 64] = fto16(-n1 * sn + n2 * cs);
    } else {                           // v heads: passthrough convert
      int hh = slot - 20;
      const float* src = row + DMODEL + 512 + hh * HD;
      unsigned short* dst = vbuf + ((size_t)(bz * NKV + hh) * SEQ + tok) * HD;
      dst[lane]      = fto16(src[lane]);
      dst[lane + 64] = fto16(src[lane + 64]);
    }
  }
}

// ---------------- flash attention: 128-row Q tile, 32-col K tiles ----------------
__global__ __launch_bounds__(256) void attn_kernel(const unsigned short* __restrict__ qb,
                                                   const unsigned short* __restrict__ kb,
                                                   const unsigned short* __restrict__ vb,
                                                   unsigned short* __restrict__ yb) {
  __shared__ unsigned short Ks[32 * 136];   // [kpos][d], padded stride
  __shared__ unsigned short Vt[128 * 40];   // [d][kpos], padded stride
  __shared__ unsigned short Ps[4][32 * 40]; // per-wave P, [row][kpos]

  const int qt = blockIdx.x;
  const int h  = blockIdx.y;
  const int bz = blockIdx.z;
  const int tid = threadIdx.x;
  const int wave = tid >> 6, lane = tid & 63;
  const int quad = lane >> 4, l16 = lane & 15;
  const int qbase = qt * 128 + wave * 32;

  const unsigned short* qg = qb + (size_t)(bz * NH + h) * SEQ * HD;
  const unsigned short* kg = kb + (size_t)(bz * NKV + (h >> 2)) * SEQ * HD;
  const unsigned short* vg = vb + (size_t)(bz * NKV + (h >> 2)) * SEQ * HD;

  bf16x8 qf[2][4];
#pragma unroll
  for (int tm = 0; tm < 2; ++tm)
#pragma unroll
    for (int ds = 0; ds < 4; ++ds)
      qf[tm][ds] = *(const bf16x8*)(qg + (size_t)(qbase + tm * 16 + l16) * HD + ds * 32 + quad * 8);

  f32x4 oacc[2][8];
#pragma unroll
  for (int i = 0; i < 2; i++)
#pragma unroll
    for (int j = 0; j < 8; j++) oacc[i][j] = f32x4{0.f, 0.f, 0.f, 0.f};

  float m_i[2][4], l_i[2][4];
#pragma unroll
  for (int i = 0; i < 2; i++)
#pragma unroll
    for (int r = 0; r < 4; r++) { m_i[i][r] = -__builtin_inff(); l_i[i][r] = 0.f; }

  const float scale = 0.08838834764831845f;   // 1/sqrt(128)
  const int nkt = qt * 4 + 4;
  const int skp = tid >> 3;        // staging kpos 0..31
  const int sd0 = (tid & 7) * 16;  // staging d offset

  for (int kt = 0; kt < nkt; ++kt) {
    __syncthreads();
    {
      const unsigned short* ksrc = kg + (size_t)(kt * 32 + skp) * HD + sd0;
      uint4 k0 = *(const uint4*)ksrc;
      uint4 k1 = *(const uint4*)(ksrc + 8);
      *(uint4*)&Ks[skp * 136 + sd0] = k0;
      *(uint4*)&Ks[skp * 136 + sd0 + 8] = k1;
      const unsigned short* vsrc = vg + (size_t)(kt * 32 + skp) * HD + sd0;
      uint4 v0 = *(const uint4*)vsrc;
      uint4 v1 = *(const uint4*)(vsrc + 8);
      unsigned short tmp[16];
      *(uint4*)&tmp[0] = v0;
      *(uint4*)&tmp[8] = v1;
#pragma unroll
      for (int j = 0; j < 16; ++j) Vt[(sd0 + j) * 40 + skp] = tmp[j];
    }
    __syncthreads();
    if (kt * 32 > qbase + 31) continue;   // wave-uniform skip; barriers stay uniform

    f32x4 sacc[2][2];
#pragma unroll
    for (int i = 0; i < 2; i++)
#pragma unroll
      for (int j = 0; j < 2; j++) sacc[i][j] = f32x4{0.f, 0.f, 0.f, 0.f};
#pragma unroll
    for (int ds = 0; ds < 4; ++ds) {
      bf16x8 b0 = *(const bf16x8*)&Ks[(l16) * 136 + ds * 32 + quad * 8];
      bf16x8 b1 = *(const bf16x8*)&Ks[(16 + l16) * 136 + ds * 32 + quad * 8];
      sacc[0][0] = __builtin_amdgcn_mfma_f32_16x16x32_bf16(qf[0][ds], b0, sacc[0][0], 0, 0, 0);
      sacc[0][1] = __builtin_amdgcn_mfma_f32_16x16x32_bf16(qf[0][ds], b1, sacc[0][1], 0, 0, 0);
      sacc[1][0] = __builtin_amdgcn_mfma_f32_16x16x32_bf16(qf[1][ds], b0, sacc[1][0], 0, 0, 0);
      sacc[1][1] = __builtin_amdgcn_mfma_f32_16x16x32_bf16(qf[1][ds], b1, sacc[1][1], 0, 0, 0);
    }

    float p[2][2][4];
    float alpha[2][4];
#pragma unroll
    for (int tm = 0; tm < 2; tm++) {
#pragma unroll
      for (int r = 0; r < 4; r++) {
        int rowg = qbase + tm * 16 + quad * 4 + r;
#pragma unroll
        for (int tn = 0; tn < 2; tn++) {
          int colg = kt * 32 + tn * 16 + l16;
          float sc = sacc[tm][tn][r] * scale;
          p[tm][tn][r] = (colg <= rowg) ? sc : -__builtin_inff();
        }
        float mx = fmaxf(p[tm][0][r], p[tm][1][r]);
        mx = fmaxf(mx, __shfl_xor(mx, 1));
        mx = fmaxf(mx, __shfl_xor(mx, 2));
        mx = fmaxf(mx, __shfl_xor(mx, 4));
        mx = fmaxf(mx, __shfl_xor(mx, 8));
        float mnew = fmaxf(m_i[tm][r], mx);
        float a = __expf(m_i[tm][r] - mnew);
        float p0 = __expf(p[tm][0][r] - mnew);
        float p1 = __expf(p[tm][1][r] - mnew);
        p[tm][0][r] = p0; p[tm][1][r] = p1;
        float rs = p0 + p1;
        rs += __shfl_xor(rs, 1);
        rs += __shfl_xor(rs, 2);
        rs += __shfl_xor(rs, 4);
        rs += __shfl_xor(rs, 8);
        l_i[tm][r] = l_i[tm][r] * a + rs;
        m_i[tm][r] = mnew;
        alpha[tm][r] = a;
      }
    }

    unsigned short* psw = &Ps[wave][0];
#pragma unroll
    for (int tm = 0; tm < 2; tm++)
#pragma unroll
      for (int tn = 0; tn < 2; tn++)
#pragma unroll
        for (int r = 0; r < 4; r++)
          psw[(tm * 16 + quad * 4 + r) * 40 + tn * 16 + l16] = fto16(p[tm][tn][r]);

#pragma unroll
    for (int tm = 0; tm < 2; tm++)
#pragma unroll
      for (int j = 0; j < 8; j++)
#pragma unroll
        for (int r = 0; r < 4; r++)
          oacc[tm][j][r] *= alpha[tm][r];

    __asm__ volatile("s_waitcnt lgkmcnt(0)" ::: "memory");  // P writes -> P reads (same wave)

    bf16x8 vf[8];
#pragma unroll
    for (int j = 0; j < 8; j++)
      vf[j] = *(const bf16x8*)&Vt[(j * 16 + l16) * 40 + quad * 8];
#pragma unroll
    for (int tm = 0; tm < 2; tm++) {
      bf16x8 pf = *(const bf16x8*)&psw[(tm * 16 + l16) * 40 + quad * 8];
#pragma unroll
      for (int j = 0; j < 8; j++)
        oacc[tm][j] = __builtin_amdgcn_mfma_f32_16x16x32_bf16(pf, vf[j], oacc[tm][j], 0, 0, 0);
    }
  }

#pragma unroll
  for (int tm = 0; tm < 2; tm++) {
#pragma unroll
    for (int r = 0; r < 4; r++) {
      float invl = 1.0f / l_i[tm][r];
      int rowg = qbase + tm * 16 + quad * 4 + r;
      size_t base = ((size_t)(bz * SEQ + rowg) * NH + h) * HD;
#pragma unroll
      for (int j = 0; j < 8; j++)
        yb[base + j * 16 + l16] = fto16(oacc[tm][j][r] * invl);
    }
  }
}

extern "C" void kernel_launch(void* const* d_in, const int* in_sizes, int n_in,
                              void* d_out, int out_size, void* d_ws, size_t ws_size,
                              hipStream_t stream) {
  (void)in_sizes; (void)n_in; (void)out_size; (void)ws_size;
  const float* x  = (const float*)d_in[0];
  const float* Wq = (const float*)d_in[1];
  const float* Wk = (const float*)d_in[2];
  const float* Wv = (const float*)d_in[3];
  const float* Wp = (const float*)d_in[4];
  const float* qg = (const float*)d_in[5];
  float* out = (float*)d_out;
  char* ws = (char*)d_ws;

  // workspace layout (108 MB); yb aliases xb (x consumed by GEMM1 before attn writes y)
  unsigned short* xb   = (unsigned short*)(ws + 0);          // 16.78 MB
  unsigned short* Wcat = (unsigned short*)(ws + 16777216);   // 12.58 MB (Wq|Wk|Wv rows)
  unsigned short* Wpq  = (unsigned short*)(ws + 29360128);   // 8.39 MB
  float*          qkv  = (float*)(ws + 37748736);            // 50.33 MB
  unsigned short* qbuf = (unsigned short*)(ws + 88080384);   // 16.78 MB
  unsigned short* kbuf = (unsigned short*)(ws + 104857600);  // 4.19 MB
  unsigned short* vbuf = (unsigned short*)(ws + 109051904);  // 4.19 MB
  unsigned short* yb   = xb;

  fq_kernel<<<32768 / 4, 256, 0, stream>>>(Wq, Wcat, 32768);
  fq_kernel<<<8192 / 4, 256, 0, stream>>>(Wk, Wcat + (size_t)2048 * 2048, 8192);
  fq_kernel<<<8192 / 4, 256, 0, stream>>>(Wv, Wcat + (size_t)2560 * 2048, 8192);
  fq_kernel<<<32768 / 4, 256, 0, stream>>>(Wp, Wpq, 32768);
  conv_kernel<<<8388608 / 1024, 256, 0, stream>>>(x, xb, 8388608);
  gemm_bt<<<dim3(32, 24), 256, 0, stream>>>(xb, Wcat, qkv, MROWS, NTOT, DMODEL);
  normrope_kernel<<<MROWS, 256, 0, stream>>>(qkv, qg, qbuf, kbuf, vbuf);
  attn_kernel<<<dim3(16, 16, 2), 256, 0, stream>>>(qbuf, kbuf, vbuf, yb);
  gemm_bt<<<dim3(32, 16), 256, 0, stream>>>(yb, Wpq, out, MROWS, DMODEL, DMODEL);
}

// Round 2
// 399.299 us; speedup vs baseline: 1.2990x; 1.2990x over previous
//
#include <hip/hip_runtime.h>
#include <hip/hip_bf16.h>
#include <hip/hip_fp16.h>

#define SEQ    2048
#define DMODEL 2048
#define NH     16
#define NKV    4
#define HD     128
#define NTOT   3072   // DMODEL + 2*NKV*HD
#define MROWS  4096   // B*SEQ

typedef __attribute__((ext_vector_type(4))) float f32x4;
typedef __attribute__((ext_vector_type(8))) __bf16 bf16x8;
typedef __attribute__((ext_vector_type(8))) unsigned short u16x8;
typedef __attribute__((ext_vector_type(4))) unsigned short u16x4;

__device__ __forceinline__ void async_copy16(const void* g, void* l) {
  __builtin_amdgcn_global_load_lds(
      (const __attribute__((address_space(1))) void*)g,
      (__attribute__((address_space(3))) void*)l, 16, 0, 0);
}

__device__ __forceinline__ unsigned short fto16(float f) {
  __hip_bfloat16 h = __float2bfloat16(f);
  return *(unsigned short*)&h;
}

// ---------------- fake-quant (all 4 weights in one launch) ----------------
__global__ __launch_bounds__(256) void fq_kernel(const float* __restrict__ Wq,
                                                 const float* __restrict__ Wk,
                                                 const float* __restrict__ Wv,
                                                 const float* __restrict__ Wp,
                                                 unsigned short* __restrict__ Wcat,
                                                 unsigned short* __restrict__ Wpq) {
  int g = blockIdx.x * 4 + (threadIdx.x >> 6);
  int lane = threadIdx.x & 63;
  const float* W;
  unsigned short* out;
  int blk;
  if (g < 32768)      { W = Wq; out = Wcat;                          blk = g; }
  else if (g < 40960) { W = Wk; out = Wcat + (size_t)2048 * 2048;    blk = g - 32768; }
  else if (g < 49152) { W = Wv; out = Wcat + (size_t)2560 * 2048;    blk = g - 40960; }
  else                { W = Wp; out = Wpq;                           blk = g - 49152; }
  const float* p = W + (size_t)blk * 128 + lane * 2;
  float w0 = p[0], w1 = p[1];
  float m = fmaxf(fabsf(w0), fabsf(w1));
#pragma unroll
  for (int o = 32; o; o >>= 1) m = fmaxf(m, __shfl_xor(m, o));
  float s = fmaxf(m / 31.0f, 1e-12f);
  s = __half2float(__float2half(s));        // fp16 RNE round of scale
  s = fmaxf(s, 6.103515625e-05f);           // fp16 tiny
  float q0 = rintf(fminf(fmaxf(w0 / s, -32.0f), 31.0f)) * s;
  float q1 = rintf(fminf(fmaxf(w1 / s, -32.0f), 31.0f)) * s;
  unsigned short* o16 = out + (size_t)blk * 128 + lane * 2;
  o16[0] = fto16(q0);
  o16[1] = fto16(q1);
}

// ---------------- fp32 -> bf16 convert ----------------
__global__ __launch_bounds__(256) void conv_kernel(const float* __restrict__ in,
                                                   unsigned short* __restrict__ out,
                                                   int n) {
  int i = (blockIdx.x * blockDim.x + threadIdx.x) * 4;
  if (i >= n) return;
  float4 v = *(const float4*)(in + i);
  ushort4 o;
  o.x = fto16(v.x); o.y = fto16(v.y); o.z = fto16(v.z); o.w = fto16(v.w);
  *(ushort4*)(out + i) = o;
}

// ---------------- bf16 MFMA GEMM, C[m,n] = sum_k A[m,k]*B[n,k] ----------------
#define BM 128
#define BN 128
#define BK 32
__global__ __launch_bounds__(256) void gemm_bt(const unsigned short* __restrict__ A,
                                               const unsigned short* __restrict__ Bm,
                                               float* __restrict__ C,
                                               int M, int N, int K) {
  __shared__ unsigned short As[BM * BK];
  __shared__ unsigned short Bs[BN * BK];
  const int tid = threadIdx.x;
  const int wave = tid >> 6, lane = tid & 63;
  const int quad = lane >> 4, l16 = lane & 15;
  const int m0 = blockIdx.x * BM, n0 = blockIdx.y * BN;
  const int wm = (wave >> 1) * 64, wn = (wave & 1) * 64;
  const int sr = lane >> 2, sc = (lane & 3) * 8;

  const unsigned short* Ag = A + (size_t)m0 * K;
  const unsigned short* Bg = Bm + (size_t)n0 * K;

  f32x4 acc[4][4];
#pragma unroll
  for (int i = 0; i < 4; i++)
#pragma unroll
    for (int j = 0; j < 4; j++) acc[i][j] = f32x4{0.f, 0.f, 0.f, 0.f};

  const int seg0 = wave * 2, seg1 = wave * 2 + 1;
  unsigned short* lA0 = &As[seg0 * 16 * BK];
  unsigned short* lA1 = &As[seg1 * 16 * BK];
  unsigned short* lB0 = &Bs[seg0 * 16 * BK];
  unsigned short* lB1 = &Bs[seg1 * 16 * BK];
  const unsigned short* gA0 = Ag + (size_t)(seg0 * 16 + sr) * K + sc;
  const unsigned short* gA1 = Ag + (size_t)(seg1 * 16 + sr) * K + sc;
  const unsigned short* gB0 = Bg + (size_t)(seg0 * 16 + sr) * K + sc;
  const unsigned short* gB1 = Bg + (size_t)(seg1 * 16 + sr) * K + sc;

  for (int k0 = 0; k0 < K; k0 += BK) {
    __syncthreads();
    async_copy16(gA0 + k0, lA0);
    async_copy16(gA1 + k0, lA1);
    async_copy16(gB0 + k0, lB0);
    async_copy16(gB1 + k0, lB1);
    __syncthreads();
    bf16x8 af[4], bf[4];
#pragma unroll
    for (int t = 0; t < 4; t++)
      af[t] = *(const bf16x8*)&As[(wm + t * 16 + l16) * BK + quad * 8];
#pragma unroll
    for (int t = 0; t < 4; t++)
      bf[t] = *(const bf16x8*)&Bs[(wn + t * 16 + l16) * BK + quad * 8];
#pragma unroll
    for (int i = 0; i < 4; i++)
#pragma unroll
      for (int j = 0; j < 4; j++)
        acc[i][j] = __builtin_amdgcn_mfma_f32_16x16x32_bf16(af[i], bf[j], acc[i][j], 0, 0, 0);
  }
#pragma unroll
  for (int i = 0; i < 4; i++) {
    int row_base = m0 + wm + i * 16 + quad * 4;
#pragma unroll
    for (int j = 0; j < 4; j++) {
      int col = n0 + wn + j * 16 + l16;
#pragma unroll
      for (int r = 0; r < 4; r++)
        C[(size_t)(row_base + r) * N + col] = acc[i][j][r];
    }
  }
}

// ---------------- RMSNorm + RoPE + gain (Q,K only), bf16 emit in (b,h,s,d) ----------------
__global__ __launch_bounds__(256) void normrope_kernel(const float* __restrict__ qkv,
                                                       const float* __restrict__ qgain,
                                                       unsigned short* __restrict__ qbuf,
                                                       unsigned short* __restrict__ kbuf) {
  const int i = blockIdx.x;            // token 0..4095
  const int bz = i >> 11, tok = i & 2047;
  const int wave = threadIdx.x >> 6, lane = threadIdx.x & 63;
  const float* row = qkv + (size_t)i * NTOT;

  double invf = pow(10000.0, -(double)(2 * lane) / 128.0);
  float freq = (float)((double)tok * invf);
  float cs = cosf(freq), sn = sinf(freq);

  for (int slot = wave; slot < 20; slot += 4) {
    if (slot < 16) {                   // q heads: norm + rope + gain
      int hh = slot;
      const float* src = row + hh * HD;
      float x1 = src[lane], x2 = src[lane + 64];
      float ss = x1 * x1 + x2 * x2;
#pragma unroll
      for (int o = 32; o; o >>= 1) ss += __shfl_xor(ss, o);
      float rn = rsqrtf(ss * (1.0f / 128.0f) + 1.1920929e-07f);
      float n1 = x1 * rn, n2 = x2 * rn;
      float g = qgain[hh];
      unsigned short* dst = qbuf + ((size_t)(bz * NH + hh) * SEQ + tok) * HD;
      dst[lane]      = fto16((n1 * cs + n2 * sn) * g);
      dst[lane + 64] = fto16((-n1 * sn + n2 * cs) * g);
    } else {                           // k heads: norm + rope
      int hh = slot - 16;
      const float* src = row + DMODEL + hh * HD;
      float x1 = src[lane], x2 = src[lane + 64];
      float ss = x1 * x1 + x2 * x2;
#pragma unroll
      for (int o = 32; o; o >>= 1) ss += __shfl_xor(ss, o);
      float rn = rsqrtf(ss * (1.0f / 128.0f) + 1.1920929e-07f);
      float n1 = x1 * rn, n2 = x2 * rn;
      unsigned short* dst = kbuf + ((size_t)(bz * NKV + hh) * SEQ + tok) * HD;
      dst[lane]      = fto16(n1 * cs + n2 * sn);
      dst[lane + 64] = fto16(-n1 * sn + n2 * cs);
    }
  }
}

// ---------------- V transpose: qkv fp32 v-section -> bf16 V^T [b,kvh,d,s] ----------------
__global__ __launch_bounds__(256) void vtrans_kernel(const float* __restrict__ qkv,
                                                     unsigned short* __restrict__ vtb) {
  __shared__ unsigned short T[64 * 72];
  const int s0 = blockIdx.x * 64;
  const int d0 = blockIdx.y * 64;
  const int bz = blockIdx.z >> 2, h = blockIdx.z & 3;
  const int tid = threadIdx.x;
#pragma unroll
  for (int i = 0; i < 2; ++i) {
    int c = i * 256 + tid;
    int s = c >> 3, ch = c & 7;
    const float* src = qkv + (size_t)(bz * SEQ + s0 + s) * NTOT + DMODEL + 512 + h * HD + d0 + ch * 8;
    float4 a = *(const float4*)src;
    float4 b = *(const float4*)(src + 4);
    u16x8 v;
    v[0] = fto16(a.x); v[1] = fto16(a.y); v[2] = fto16(a.z); v[3] = fto16(a.w);
    v[4] = fto16(b.x); v[5] = fto16(b.y); v[6] = fto16(b.z); v[7] = fto16(b.w);
    *(u16x8*)&T[s * 72 + ch * 8] = v;
  }
  __syncthreads();
  unsigned short* outg = vtb + (size_t)(bz * NKV + h) * HD * SEQ;
#pragma unroll
  for (int i = 0; i < 2; ++i) {
    int c = i * 256 + tid;
    int d = c >> 3, sc = c & 7;
    u16x8 v;
#pragma unroll
    for (int j = 0; j < 8; ++j) v[j] = T[(sc * 8 + j) * 72 + d];
    *(u16x8*)(outg + (size_t)(d0 + d) * SEQ + s0 + sc * 8) = v;
  }
}

// ---------------- flash attention: S^T formulation, paired causal tiles ----------------
#define KT 64
#define KS_ST 136
#define VT_ST 72
#define PS_ST 72
__global__ __launch_bounds__(256) void attn_kernel(const unsigned short* __restrict__ qb,
                                                   const unsigned short* __restrict__ kb,
                                                   const unsigned short* __restrict__ vtb,
                                                   unsigned short* __restrict__ yb) {
  __shared__ unsigned short Ks[KT * KS_ST];      // [kpos][d]
  __shared__ unsigned short Vt[HD * VT_ST];      // [d][kpos]
  __shared__ unsigned short Ps[4][16 * PS_ST];   // per-wave P [row16][kpos]

  const int pair = blockIdx.x;   // 0..15 -> qtiles {pair, 31-pair}
  const int h = blockIdx.y;
  const int bz = blockIdx.z;
  const int tid = threadIdx.x;
  const int wave = tid >> 6, lane = tid & 63;
  const int quad = lane >> 4, l16 = lane & 15;

  const unsigned short* qg = qb + (size_t)(bz * NH + h) * SEQ * HD;
  const unsigned short* kg = kb + (size_t)(bz * NKV + (h >> 2)) * SEQ * HD;
  const unsigned short* vg = vtb + (size_t)(bz * NKV + (h >> 2)) * HD * SEQ;

  const float scale = 0.08838834764831845f;   // 1/sqrt(128)
  const int qts[2] = {pair, 31 - pair};

  for (int ti = 0; ti < 2; ++ti) {
    const int qt = qts[ti];
    const int q0 = qt * 64;
    const int qrow = q0 + wave * 16 + l16;     // softmax row owned by this lane

    bf16x8 qf[4];
#pragma unroll
    for (int ds = 0; ds < 4; ++ds)
      qf[ds] = *(const bf16x8*)(qg + (size_t)qrow * HD + ds * 32 + quad * 8);

    f32x4 oacc[8];
#pragma unroll
    for (int j = 0; j < 8; ++j) oacc[j] = f32x4{0.f, 0.f, 0.f, 0.f};
    float m_i = -__builtin_inff(), l_i = 0.f;

    const int nkt = qt + 1;
    for (int kt = 0; kt < nkt; ++kt) {
      __syncthreads();
#pragma unroll
      for (int i = 0; i < 4; ++i) {            // stage K: 64 kpos x 128 d
        int c = i * 256 + tid;
        int row = c >> 4, ch = c & 15;
        u16x8 v = *(const u16x8*)(kg + (size_t)(kt * 64 + row) * HD + ch * 8);
        *(u16x8*)&Ks[row * KS_ST + ch * 8] = v;
      }
#pragma unroll
      for (int i = 0; i < 4; ++i) {            // stage V^T: 128 d x 64 kpos
        int c = i * 256 + tid;
        int d = c >> 3, ch = c & 7;
        u16x8 v = *(const u16x8*)(vg + (size_t)d * SEQ + kt * 64 + ch * 8);
        *(u16x8*)&Vt[d * VT_ST + ch * 8] = v;
      }
      __syncthreads();

      // S^T = K * Q^T  (q registers double as the B operand)
      f32x4 st[4];
#pragma unroll
      for (int mt = 0; mt < 4; ++mt) {
        st[mt] = f32x4{0.f, 0.f, 0.f, 0.f};
#pragma unroll
        for (int ds = 0; ds < 4; ++ds) {
          bf16x8 kf = *(const bf16x8*)&Ks[(mt * 16 + l16) * KS_ST + ds * 32 + quad * 8];
          st[mt] = __builtin_amdgcn_mfma_f32_16x16x32_bf16(kf, qf[ds], st[mt], 0, 0, 0);
        }
      }

      // mask + online softmax (lane-local row)
      float p[4][4];
      float mx = -__builtin_inff();
#pragma unroll
      for (int mt = 0; mt < 4; ++mt)
#pragma unroll
        for (int r = 0; r < 4; ++r) {
          int kp = kt * 64 + mt * 16 + quad * 4 + r;
          float v = st[mt][r] * scale;
          v = (kp <= qrow) ? v : -__builtin_inff();
          p[mt][r] = v;
          mx = fmaxf(mx, v);
        }
      mx = fmaxf(mx, __shfl_xor(mx, 16));
      mx = fmaxf(mx, __shfl_xor(mx, 32));
      float mnew = fmaxf(m_i, mx);
      float a = __expf(m_i - mnew);
      float rs = 0.f;
#pragma unroll
      for (int mt = 0; mt < 4; ++mt)
#pragma unroll
        for (int r = 0; r < 4; ++r) {
          float e = __expf(p[mt][r] - mnew);
          p[mt][r] = e;
          rs += e;
        }
      rs += __shfl_xor(rs, 16);
      rs += __shfl_xor(rs, 32);
      l_i = l_i * a + rs;
      m_i = mnew;

      // vectorized P store: 4 consecutive kpos per write
#pragma unroll
      for (int mt = 0; mt < 4; ++mt) {
        u16x4 pk;
#pragma unroll
        for (int r = 0; r < 4; ++r) pk[r] = fto16(p[mt][r]);
        *(u16x4*)&Ps[wave][l16 * PS_ST + mt * 16 + quad * 4] = pk;
      }

      // broadcast alpha to C-layout rows, rescale O
      float ar[4];
#pragma unroll
      for (int r = 0; r < 4; ++r) ar[r] = __shfl(a, quad * 4 + r);
#pragma unroll
      for (int j = 0; j < 8; ++j)
#pragma unroll
        for (int r = 0; r < 4; ++r) oacc[j][r] *= ar[r];

      __asm__ volatile("s_waitcnt lgkmcnt(0)" ::: "memory");  // P writes visible to own reads

      // O += P * V
#pragma unroll
      for (int c = 0; c < 2; ++c) {
        bf16x8 pf = *(const bf16x8*)&Ps[wave][l16 * PS_ST + c * 32 + quad * 8];
#pragma unroll
        for (int j = 0; j < 8; ++j) {
          bf16x8 vf = *(const bf16x8*)&Vt[(j * 16 + l16) * VT_ST + c * 32 + quad * 8];
          oacc[j] = __builtin_amdgcn_mfma_f32_16x16x32_bf16(pf, vf, oacc[j], 0, 0, 0);
        }
      }
    }

    // epilogue
    float il = 1.0f / l_i;
    float ilr[4];
#pragma unroll
    for (int r = 0; r < 4; ++r) ilr[r] = __shfl(il, quad * 4 + r);
#pragma unroll
    for (int j = 0; j < 8; ++j)
#pragma unroll
      for (int r = 0; r < 4; ++r) {
        int rowg = q0 + wave * 16 + quad * 4 + r;
        yb[(size_t)(bz * SEQ + rowg) * DMODEL + h * HD + j * 16 + l16] =
            fto16(oacc[j][r] * ilr[r]);
      }
  }
}

extern "C" void kernel_launch(void* const* d_in, const int* in_sizes, int n_in,
                              void* d_out, int out_size, void* d_ws, size_t ws_size,
                              hipStream_t stream) {
  (void)in_sizes; (void)n_in; (void)out_size; (void)ws_size;
  const float* x  = (const float*)d_in[0];
  const float* Wq = (const float*)d_in[1];
  const float* Wk = (const float*)d_in[2];
  const float* Wv = (const float*)d_in[3];
  const float* Wp = (const float*)d_in[4];
  const float* qg = (const float*)d_in[5];
  float* out = (float*)d_out;
  char* ws = (char*)d_ws;

  // workspace layout; yb aliases xb (x consumed by GEMM1 before attn writes y)
  unsigned short* xb   = (unsigned short*)(ws + 0);          // 16.78 MB
  unsigned short* Wcat = (unsigned short*)(ws + 16777216);   // 12.58 MB (Wq|Wk|Wv rows)
  unsigned short* Wpq  = (unsigned short*)(ws + 29360128);   // 8.39 MB
  float*          qkv  = (float*)(ws + 37748736);            // 50.33 MB
  unsigned short* qbuf = (unsigned short*)(ws + 88080384);   // 16.78 MB
  unsigned short* kbuf = (unsigned short*)(ws + 104857600);  // 4.19 MB
  unsigned short* vtb  = (unsigned short*)(ws + 109051904);  // 4.19 MB (V^T)
  unsigned short* yb   = xb;

  fq_kernel<<<81920 / 4, 256, 0, stream>>>(Wq, Wk, Wv, Wp, Wcat, Wpq);
  conv_kernel<<<8388608 / 1024, 256, 0, stream>>>(x, xb, 8388608);
  gemm_bt<<<dim3(32, 24), 256, 0, stream>>>(xb, Wcat, qkv, MROWS, NTOT, DMODEL);
  normrope_kernel<<<MROWS, 256, 0, stream>>>(qkv, qg, qbuf, kbuf);
  vtrans_kernel<<<dim3(32, 2, 8), 256, 0, stream>>>(qkv, vtb);
  attn_kernel<<<dim3(16, NH, 2), 256, 0, stream>>>(qbuf, kbuf, vtb, yb);
  gemm_bt<<<dim3(32, 16), 256, 0, stream>>>(yb, Wpq, out, MROWS, DMODEL, DMODEL);
}